// Round 9
// baseline (315.270 us; speedup 1.0000x reference)
//
#include <hip/hip_runtime.h>
#include <hip/hip_bf16.h>
#include <cmath>

// Problem constants
constexpr int Bc = 128, Tc = 128, Ac = 16;
constexpr int Dc = 256, Hc = 512, Qc = 128, QIc = 512, Vc = 64, NTk = 13;
// Masked logits: ref emits -inf; harness needs finite there.
constexpr float NEG_BIG = -1e30f;
// fp8 scaling: weights x16, activations x16 (exact pow2).
// Descale folded into the MX scale operand (exact pow2 -> bitwise-equiv math):
//   L1/L2: scale 2^-4 -> acc = 16*W*X ; epilogue s = acc + 16*b
//   L3/Q : scale 2^-8 -> acc = W*X    ; epilogue s = acc + b
constexpr float ACT_SCALE = 16.f;

typedef unsigned int uint;
typedef uint uint2v __attribute__((ext_vector_type(2)));
typedef int i32x8 __attribute__((ext_vector_type(8)));
typedef float f32x4 __attribute__((ext_vector_type(4)));
typedef float f32x16 __attribute__((ext_vector_type(16)));

// MX-scaled fp8 MFMA. Uniform scale dword -> mapping-independent.
// 0x7F = 2^0, 0x7B = 2^-4, 0x77 = 2^-8 (E8M0). Verified r6-r8.
#define MFMA32S(a, b, c, SA) __builtin_amdgcn_mfma_scale_f32_32x32x64_f8f6f4( \
    (a), (b), (c), 0, 0, 0, (int)(SA), 0, 0x7F7F7F7F)
#define MFMA128Q(a, b, c) __builtin_amdgcn_mfma_scale_f32_16x16x128_f8f6f4( \
    (a), (b), (c), 0, 0, 0, 0x77777777, 0, 0x7F7F7F7F)

__device__ __forceinline__ unsigned short f2bfu(float f) {
  __hip_bfloat16 h = __float2bfloat16(f);
  return *(unsigned short*)&h;
}
__device__ __forceinline__ float bf2f(short s) {
  return __uint_as_float(((unsigned)(unsigned short)s) << 16);
}
__device__ __forceinline__ uint pack4_fp8(float a, float b, float c, float d) {
  uint v = 0;
  v = __builtin_amdgcn_cvt_pk_fp8_f32(a, b, v, 0);
  v = __builtin_amdgcn_cvt_pk_fp8_f32(c, d, v, 1);
  return v;
}

// ---------------------------------------------------------------------------
// Weight transform: fp32 [P][K][N] -> fp8 (x16) MFMA A-fragments.
// kW1/kW2/kW3: 32x32x64 frags: n = nt*32 + (lane&31), k = kc*64 + (lane>>5)*32 + byte.
// qW:          16x16x128 frags: n = nt*16 + (lane&15), k = kc*128 + (lane>>4)*32 + byte.
// Verified r1-r8 (A/B share one lane->k bijection; k-permutation-invariant).
// ---------------------------------------------------------------------------
__global__ void transform_all(const float* __restrict__ kW1, const float* __restrict__ kW2,
                              const float* __restrict__ kW3, const float* __restrict__ qW,
                              int* __restrict__ kW1f, int* __restrict__ kW2f,
                              int* __restrict__ kW3f, int* __restrict__ qWf) {
  int id = blockIdx.x * 256 + threadIdx.x;  // 131072 total
  int jh = id >> 16;                        // 0/1: 16B half of the 32B lane chunk
  int gid = id & 65535;
  const float* W;
  int* dst;
  int NT, KC, N, local;
  bool big;  // 32x32 layout?
  if (gid < 16384) {            // kW1: P4 x NT16 x KC4 (32x32)
    W = kW1; dst = kW1f; NT = 16; KC = 4; N = 512; local = gid; big = true;
  } else if (gid < 49152) {     // kW2: P4 x NT16 x KC8 (32x32)
    W = kW2; dst = kW2f; NT = 16; KC = 8; N = 512; local = gid - 16384; big = true;
  } else if (gid < 57344) {     // kW3: P4 x NT4 x KC8 (32x32)
    W = kW3; dst = kW3f; NT = 4; KC = 8; N = 128; local = gid - 49152; big = true;
  } else {                      // qW:  P4 x NT8 x KC4 (16x16)
    W = qW; dst = qWf; NT = 8; KC = 4; N = 128; local = gid - 57344; big = false;
  }
  int lane = local & 63;
  int frag = local >> 6;
  int kc = frag % KC;
  int rest = frag / KC;
  int nt = rest % NT;
  int pp = rest / NT;
  int K = KC * (big ? 64 : 128);
  int n, k0;
  if (big) { n = nt * 32 + (lane & 31); k0 = kc * 64 + (lane >> 5) * 32; }
  else     { n = nt * 16 + (lane & 15); k0 = kc * 128 + (lane >> 4) * 32; }
  k0 += jh * 16;
  const float* src = W + ((size_t)pp * K + k0) * N + n;
  int4 v;
  int vv[4];
#pragma unroll
  for (int jj = 0; jj < 4; ++jj) {
    float f0 = src[(size_t)(4 * jj + 0) * N] * ACT_SCALE;
    float f1 = src[(size_t)(4 * jj + 1) * N] * ACT_SCALE;
    float f2 = src[(size_t)(4 * jj + 2) * N] * ACT_SCALE;
    float f3 = src[(size_t)(4 * jj + 3) * N] * ACT_SCALE;
    vv[jj] = (int)pack4_fp8(f0, f1, f2, f3);
  }
  v.x = vv[0]; v.y = vv[1]; v.z = vv[2]; v.w = vv[3];
  *(int4*)(dst + (size_t)local * 8 + jh * 4) = v;
}

// ---------------------------------------------------------------------------
// 32x32x64 MX fp8 MFMA layer — occupancy build (32 waves/CU, r5 regime).
// kc=0 PEELED with caller-prefetched wv0 issued just before the preceding
// __syncthreads (barrier vmcnt drain absorbs cold L2 latency; r8 +2%).
// r9: 32B-CHUNK XOR swizzle on H buffers (SWZI read / SWZO write):
//   chunk_byte ^= ((row>>3)&3) << 5.
// Why 32B (not r6's 16B): bank shifts come in multiples of 8 dwords, which
// keeps every b128 read at the 4-dword/bank minimum (chunk permutation; both
// uint4s of a 32B fragment stay in one chunk) while spreading the epilogue
// ds_write_b32 from 8 banks (8-way conflict — rows r,r+8,r+16,r+24 collide
// at bank 4*(row&7): ~6.3M of the 7.6M counter) to 16 banks (4-way, the
// structural floor for 16B-aligned strides). r6's <<4 variant shifted banks
// by 4 -> left writes 4-way AND doubled read conflicts (18M measured).
// Swizzle depends only on row mod 32 -> reader (lane&31) and writer
// (at*32+row) agree. Xs/KV/beAb stay linear/as-verified.
// B-frag: lane (row=lane&31, q=lane>>5) reads 32B at row(+32*at), chunk
// q*32 + kc*64 (^swz). C/D: lane = action col; n = nt*32+(reg&3)+8*(reg>>2)+4q.
// OUTMODE: 0 = fp8 x16 hidden (s = acc + 16b, relu), 1 = bf16 KV (s = acc + b).
// ---------------------------------------------------------------------------
template <int KC, int AT, bool RELU, int OUTMODE, int SIN, int SOUT,
          bool SWZI, bool SWZO, unsigned SA>
__device__ __forceinline__ void layer32r(
    const char* __restrict__ aB, void* __restrict__ o0,
    const int* __restrict__ Wfi, const float* __restrict__ bias,
    int nt0, int at0, int lane, i32x8 wv0) {
  const int row = lane & 31, q = lane >> 5;
  const unsigned swzi = SWZI ? (((unsigned)(row >> 3) & 3u) << 5) : 0u;
  const char* apR = aB + row * SIN + at0 * 32 * SIN;
  const int* wp = Wfi + (size_t)nt0 * KC * 512 + lane * 8;

  f32x16 acc[AT];
#pragma unroll
  for (int at = 0; at < AT; ++at)
#pragma unroll
    for (int r = 0; r < 16; ++r) acc[at][r] = 0.f;

  // ---- kc = 0 peeled: consumes the pre-barrier prefetched wv0 ----
#pragma unroll
  for (int at = 0; at < AT; ++at) {
    const char* pa = apR + at * 32 * SIN + (((unsigned)(q * 32)) ^ swzi);
    uint4 u0 = *(const uint4*)(pa);
    uint4 u1 = *(const uint4*)(pa + 16);
    i32x8 bf;
    bf[0] = (int)u0.x; bf[1] = (int)u0.y; bf[2] = (int)u0.z; bf[3] = (int)u0.w;
    bf[4] = (int)u1.x; bf[5] = (int)u1.y; bf[6] = (int)u1.z; bf[7] = (int)u1.w;
    acc[at] = MFMA32S(wv0, bf, acc[at], SA);
  }

#pragma unroll 1
  for (int kc = 1; kc < KC; ++kc) {
    i32x8 wv = *(const i32x8*)(wp + kc * 512);
#pragma unroll
    for (int at = 0; at < AT; ++at) {
      const char* pa = apR + at * 32 * SIN + (((unsigned)(q * 32 + kc * 64)) ^ swzi);
      uint4 u0 = *(const uint4*)(pa);
      uint4 u1 = *(const uint4*)(pa + 16);
      i32x8 bf;
      bf[0] = (int)u0.x; bf[1] = (int)u0.y; bf[2] = (int)u0.z; bf[3] = (int)u0.w;
      bf[4] = (int)u1.x; bf[5] = (int)u1.y; bf[6] = (int)u1.z; bf[7] = (int)u1.w;
      acc[at] = MFMA32S(wv, bf, acc[at], SA);
    }
  }

#pragma unroll
  for (int at = 0; at < AT; ++at) {
    const int rowout = (at0 + at) * 32 + row;
    const unsigned swzo = SWZO ? (((unsigned)(rowout >> 3) & 3u) << 5) : 0u;
    const int tb = nt0 * 32 + 4 * q;
#pragma unroll
    for (int j = 0; j < 4; ++j) {
      const unsigned nb = (unsigned)(tb + 8 * j);  // 4 consecutive outdims
      float4 bv = *(const float4*)(bias + nb);
      if (OUTMODE == 0) {
        float s0 = fmaf(bv.x, 16.f, acc[at][4 * j + 0]);
        float s1 = fmaf(bv.y, 16.f, acc[at][4 * j + 1]);
        float s2 = fmaf(bv.z, 16.f, acc[at][4 * j + 2]);
        float s3 = fmaf(bv.w, 16.f, acc[at][4 * j + 3]);
        if (RELU) {
          s0 = fmaxf(s0, 0.f); s1 = fmaxf(s1, 0.f);
          s2 = fmaxf(s2, 0.f); s3 = fmaxf(s3, 0.f);
        }
        *(uint*)((char*)o0 + rowout * SOUT + (nb ^ swzo)) = pack4_fp8(s0, s1, s2, s3);
      } else {
        float s0 = acc[at][4 * j + 0] + bv.x;
        float s1 = acc[at][4 * j + 1] + bv.y;
        float s2 = acc[at][4 * j + 2] + bv.z;
        float s3 = acc[at][4 * j + 3] + bv.w;
        uint2v u;
        u.x = ((uint)f2bfu(s1) << 16) | f2bfu(s0);
        u.y = ((uint)f2bfu(s3) << 16) | f2bfu(s2);
        *(uint2v*)((short*)o0 + rowout * SOUT + nb) = u;
      }
    }
  }
}

// ---------------------------------------------------------------------------
// 16x16x128 query head, rolled (waves 8-15, runs beside L3). Verified layout.
// Scale 2^-8 folded -> plain add epilogue. kc=0 peeled with prefetched wv0.
// ---------------------------------------------------------------------------
template <int KC, int SIN, int SOUT, int CMASK>
__device__ __forceinline__ void layer128r(
    const char* __restrict__ aB, float* __restrict__ o0,
    const int* __restrict__ Wfi, const float* __restrict__ bias,
    int nt0, int lane, i32x8 wv0) {
  const int c = lane & 15, q = lane >> 4;
  const int sw = (c & 1) << 4;
  const char* ap = aB + (c & CMASK) * SIN + q * 32;
  const int* wp = Wfi + (size_t)nt0 * KC * 512 + lane * 8;

  f32x4 acc;
#pragma unroll
  for (int r = 0; r < 4; ++r) acc[r] = 0.f;

  {
    uint4 u0 = *(const uint4*)(ap + sw);
    uint4 u1 = *(const uint4*)(ap + (16 ^ sw));
    i32x8 bf;
    bf[0] = (int)u0.x; bf[1] = (int)u0.y; bf[2] = (int)u0.z; bf[3] = (int)u0.w;
    bf[4] = (int)u1.x; bf[5] = (int)u1.y; bf[6] = (int)u1.z; bf[7] = (int)u1.w;
    acc = MFMA128Q(wv0, bf, acc);
  }

#pragma unroll 1
  for (int kc = 1; kc < KC; ++kc) {
    i32x8 wv = *(const i32x8*)(wp + kc * 512);
    const char* pa = ap + kc * 128;
    uint4 u0 = *(const uint4*)(pa + sw);
    uint4 u1 = *(const uint4*)(pa + (16 ^ sw));
    i32x8 bf;
    bf[0] = (int)u0.x; bf[1] = (int)u0.y; bf[2] = (int)u0.z; bf[3] = (int)u0.w;
    bf[4] = (int)u1.x; bf[5] = (int)u1.y; bf[6] = (int)u1.z; bf[7] = (int)u1.w;
    acc = MFMA128Q(wv, bf, acc);
  }

  const int nb = nt0 * 16 + 4 * q;
  float4 bv = *(const float4*)(bias + nb);
  if (c < 4) {  // only real token rows
    float4 st;
    st.x = acc[0] + bv.x;
    st.y = acc[1] + bv.y;
    st.z = acc[2] + bv.z;
    st.w = acc[3] + bv.w;
    *(float4*)(o0 + c * SOUT + nb) = st;
  }
}

// ---------------------------------------------------------------------------
// Main fused kernel: 1024 threads (16 waves), 64 rows (4 tokens x 16 actions).
// launch_bounds(1024,8): VGPR cap 64 -> 2 blocks/CU = 32 waves/CU (HW max).
// Each layer's kc=0 weight fragment is loaded just BEFORE the preceding
// barrier (short live range). H1/H2 use the 32B-chunk XOR swizzle (r9).
// phase = blockIdx&3: per-XCD one phase, 512KB fp8 weight set L2-resident.
// ---------------------------------------------------------------------------
constexpr int SX = 272;   // Xs row stride bytes  (256 data + 16; ==16 mod 128)
constexpr int SH = 528;   // H1/H2 row stride     (512 data + 16; ==16 mod 128)
constexpr int SBE = 544;  // beAb row stride (16x16 path, (c&1) swizzled)
constexpr int SKV = 136;  // KV stride (bf16 elems, linear)
constexpr int SQY = 132;  // QY stride (fp32 elems, linear)

__global__ __launch_bounds__(1024, 8) void policy_main(
    const float* __restrict__ be, const int* __restrict__ va,
    const int* __restrict__ phase, const int* __restrict__ trick,
    const float* __restrict__ emb0, const float* __restrict__ emb1,
    const float* __restrict__ emb2, const float* __restrict__ ln_g,
    const float* __restrict__ ln_b,
    const float* __restrict__ kb1, const float* __restrict__ kb2,
    const float* __restrict__ kb3, const float* __restrict__ qb,
    const int* __restrict__ kW1f, const int* __restrict__ kW2f,
    const int* __restrict__ kW3f, const int* __restrict__ qWf,
    float* __restrict__ out) {
  __shared__ __align__(16) char bufA[64 * SH];   // Xs [64][SX] then H2 [64][SH]
  __shared__ __align__(16) char bufB[64 * SH];   // H1 [64][SH]; then KV [64][SKV] bf16
  __shared__ __align__(16) char beAb[4 * SBE];   // be tokens fp8 (4 rows, swizzled)
  __shared__ __align__(16) float QYs[4 * SQY];
  __shared__ float attn_s[64];
  __shared__ int inval_s[64];
  __shared__ int ph_s[4], tr_s[4];

  char* Xs = bufA;
  char* H2 = bufA;
  char* H1 = bufB;
  short* KV = (short*)bufB;  // H1 dead after layer2

  const int tid = threadIdx.x;
  const int lane = tid & 63;
  const int wu = __builtin_amdgcn_readfirstlane(tid >> 6);  // wave id -> SGPR
  const int p = blockIdx.x & 3;
  const int g = blockIdx.x >> 2;
  const int b = g >> 3;
  const int t0 = p * 32 + (g & 7) * 4;
  const int bt0 = b * Tc + t0;

  // ---- stage 0 (no internal barrier): masks, phase/trick, beA, LN->Xs ----
  if (tid < 64) {
    inval_s[tid] = (va[((size_t)bt0 * Ac + tid) * 3] == -1);
  } else if (tid < 68) {
    ph_s[tid - 64] = phase[bt0 + tid - 64];
  } else if (tid < 72) {
    tr_s[tid - 68] = trick[bt0 + tid - 68];
  }
  if (tid < 128) {  // beA: 4 token rows x 512 dims fp8 (x16), swizzled 16B units
    const int tok = tid >> 5, li = tid & 31;
    const float4* bp4 = (const float4*)(be + ((size_t)(bt0 + tok)) * QIc + li * 16);
    float4 a0 = bp4[0], a1 = bp4[1], a2 = bp4[2], a3 = bp4[3];
    uint4 v;
    v.x = pack4_fp8(a0.x * ACT_SCALE, a0.y * ACT_SCALE, a0.z * ACT_SCALE, a0.w * ACT_SCALE);
    v.y = pack4_fp8(a1.x * ACT_SCALE, a1.y * ACT_SCALE, a1.z * ACT_SCALE, a1.w * ACT_SCALE);
    v.z = pack4_fp8(a2.x * ACT_SCALE, a2.y * ACT_SCALE, a2.z * ACT_SCALE, a2.w * ACT_SCALE);
    v.w = pack4_fp8(a3.x * ACT_SCALE, a3.y * ACT_SCALE, a3.z * ACT_SCALE, a3.w * ACT_SCALE);
    *(uint4*)(beAb + tok * SBE + ((li * 16) ^ ((tok & 1) << 4))) = v;
  }
  {
    // embed-sum + LayerNorm -> Xs fp8 x16 (16 thr/row x 16 dims), linear layout
    const int r = tid >> 4, part = tid & 15, d0 = part * 16;
    const int* vp = va + ((size_t)bt0 * Ac + r) * 3;
    int i0 = min(max(vp[0], 0), Vc - 1);
    int i1 = min(max(vp[1], 0), Vc - 1);
    int i2 = min(max(vp[2], 0), Vc - 1);
    const float4* e0 = (const float4*)(emb0 + i0 * Dc + d0);
    const float4* e1 = (const float4*)(emb1 + i1 * Dc + d0);
    const float4* e2 = (const float4*)(emb2 + i2 * Dc + d0);
    float xv[16];
    float sum = 0.f, ss = 0.f;
#pragma unroll
    for (int j = 0; j < 4; ++j) {
      float4 v0 = e0[j], v1 = e1[j], v2 = e2[j];
      float4 v;
      v.x = v0.x + v1.x + v2.x; v.y = v0.y + v1.y + v2.y;
      v.z = v0.z + v1.z + v2.z; v.w = v0.w + v1.w + v2.w;
      xv[j * 4 + 0] = v.x; xv[j * 4 + 1] = v.y; xv[j * 4 + 2] = v.z; xv[j * 4 + 3] = v.w;
      sum += v.x + v.y + v.z + v.w;
      ss += v.x * v.x + v.y * v.y + v.z * v.z + v.w * v.w;
    }
    sum += __shfl_xor(sum, 1); sum += __shfl_xor(sum, 2);
    sum += __shfl_xor(sum, 4); sum += __shfl_xor(sum, 8);
    ss += __shfl_xor(ss, 1);   ss += __shfl_xor(ss, 2);
    ss += __shfl_xor(ss, 4);   ss += __shfl_xor(ss, 8);
    const float mu = sum / (float)Dc;
    const float rstd = rsqrtf(ss / (float)Dc - mu * mu + 1e-5f);
    uint dw[4];
#pragma unroll
    for (int j = 0; j < 4; ++j) {
      float4 gg = *(const float4*)(ln_g + d0 + 4 * j);
      float4 bb = *(const float4*)(ln_b + d0 + 4 * j);
      float y0 = ((xv[4 * j + 0] - mu) * rstd * gg.x + bb.x) * ACT_SCALE;
      float y1 = ((xv[4 * j + 1] - mu) * rstd * gg.y + bb.y) * ACT_SCALE;
      float y2 = ((xv[4 * j + 2] - mu) * rstd * gg.z + bb.z) * ACT_SCALE;
      float y3 = ((xv[4 * j + 3] - mu) * rstd * gg.w + bb.w) * ACT_SCALE;
      dw[j] = pack4_fp8(y0, y1, y2, y3);
    }
    uint4 v;
    v.x = dw[0]; v.y = dw[1]; v.z = dw[2]; v.w = dw[3];
    *(uint4*)(Xs + r * SX + d0) = v;
  }

  // ---- L1 kc=0 prefetch: issued just before the barrier (short live range;
  //      latency folds into the barrier's vmcnt drain) ----
  const int* w1base = kW1f + (size_t)p * 32768;
  i32x8 w1 = *(const i32x8*)(w1base + (size_t)wu * 4 * 512 + lane * 8);
  __syncthreads();

  // ---- layer1: X(64x256) @ kW1 -> H1(64x512) relu. 16 waves x 1nt x 2at ----
  layer32r<4, 2, true, 0, SX, SH, false, true, 0x7B7B7B7Bu>(
      Xs, H1, w1base, kb1 + p * Hc, wu, 0, lane, w1);

  // ---- L2 kc=0 prefetch (pre-barrier; acc regs are dead here) ----
  const int* w2base = kW2f + (size_t)p * 65536;
  i32x8 w2 = *(const i32x8*)(w2base + (size_t)wu * 8 * 512 + lane * 8);
  __syncthreads();

  // ---- layer2: H1(64x512) @ kW2 -> H2(64x512) relu ----
  layer32r<8, 2, true, 0, SH, SH, true, true, 0x7B7B7B7Bu>(
      H1, H2, w2base, kb2 + p * Hc, wu, 0, lane, w2);

  // ---- L3/q kc=0 prefetch (wave-uniform select, pre-barrier) ----
  const int* w3base = (wu < 8) ? (kW3f + (size_t)p * 16384) : (qWf + (size_t)p * 16384);
  const int w3off = (wu < 8) ? ((wu >> 1) * 8 * 512) : ((wu - 8) * 4 * 512);
  i32x8 w3 = *(const i32x8*)(w3base + (size_t)w3off + lane * 8);
  __syncthreads();

  // ---- layer3 (waves 0-7) -> KV bf16 ; query (waves 8-15) -> QY fp32 ----
  if (wu < 8) {
    layer32r<8, 1, false, 1, SH, SKV, true, false, 0x77777777u>(
        H2, (void*)KV, w3base, kb3 + p * Qc, wu >> 1, wu & 1, lane, w3);
  } else {
    layer128r<4, SBE, SQY, 3>(beAb, QYs, w3base, qb + p * Qc, wu - 8, lane, w3);
  }
  __syncthreads();

  // ---- attn[r] = <QY[tok], KV[r]> / sqrt(Q) (16 thr/row x 8 dims) ----
  {
    const int r = tid >> 4, part = tid & 15, tok = r >> 4;
    uint4 kk = *(const uint4*)(KV + r * SKV + part * 8);
    const float4* qp4 = (const float4*)(QYs + tok * SQY + part * 8);
    float4 q0 = qp4[0], q1 = qp4[1];
    float s = 0.f;
    s += bf2f((short)(kk.x & 0xffff)) * q0.x;
    s += bf2f((short)(kk.x >> 16)) * q0.y;
    s += bf2f((short)(kk.y & 0xffff)) * q0.z;
    s += bf2f((short)(kk.y >> 16)) * q0.w;
    s += bf2f((short)(kk.z & 0xffff)) * q1.x;
    s += bf2f((short)(kk.z >> 16)) * q1.y;
    s += bf2f((short)(kk.w & 0xffff)) * q1.z;
    s += bf2f((short)(kk.w >> 16)) * q1.w;
    s += __shfl_xor(s, 1); s += __shfl_xor(s, 2);
    s += __shfl_xor(s, 4); s += __shfl_xor(s, 8);
    if (part == 0) attn_s[r] = s * 0.08838834764831845f;  // 1/sqrt(128)
  }
  __syncthreads();

  // ---- mask, signal weight, log_softmax, store (wave-parallel: 16 thr/token) ----
  if (tid < 64) {
    const int tok = tid >> 4, a = tid & 15;
    const int bt = bt0 + tok;
    const int iv = inval_s[tid];
    float av = iv ? NEG_BIG : attn_s[tid];
    int inv = iv;
    inv += __shfl_xor(inv, 1); inv += __shfl_xor(inv, 2);
    inv += __shfl_xor(inv, 4); inv += __shfl_xor(inv, 8);
    const int nv = 16 - inv;
    if (a == 0 && ph_s[tok] == 1) {
      const int nt = NTk - tr_s[tok];
      float dp = 1.f;
      for (int i = 0; i < nt; ++i) dp *= 0.6f;
      const float ps = 0.4f / (1.f - dp);
      float wgt = (nv == 1) ? 0.f : logf(fmaxf((1.f - ps) / ps * ((float)nv - 1.f), 1e-5f));
      av += wgt;
    }
    float m = av;
    m = fmaxf(m, __shfl_xor(m, 1)); m = fmaxf(m, __shfl_xor(m, 2));
    m = fmaxf(m, __shfl_xor(m, 4)); m = fmaxf(m, __shfl_xor(m, 8));
    float e = expf(av - m);
    float se = e;
    se += __shfl_xor(se, 1); se += __shfl_xor(se, 2);
    se += __shfl_xor(se, 4); se += __shfl_xor(se, 8);
    const float lse = logf(se) + m;
    out[bt * Ac + a] = iv ? NEG_BIG : (av - lse);
  }
}

extern "C" void kernel_launch(void* const* d_in, const int* in_sizes, int n_in,
                              void* d_out, int out_size, void* d_ws, size_t ws_size,
                              hipStream_t stream) {
  const float* be   = (const float*)d_in[0];
  const int*   va   = (const int*)d_in[1];
  const int*   ph   = (const int*)d_in[2];
  const int*   tr   = (const int*)d_in[3];
  const float* emb0 = (const float*)d_in[4];
  const float* emb1 = (const float*)d_in[5];
  const float* emb2 = (const float*)d_in[6];
  const float* lng  = (const float*)d_in[7];
  const float* lnb  = (const float*)d_in[8];
  const float* kW1  = (const float*)d_in[9];
  const float* kb1  = (const float*)d_in[10];
  const float* kW2  = (const float*)d_in[11];
  const float* kb2  = (const float*)d_in[12];
  const float* kW3  = (const float*)d_in[13];
  const float* kb3  = (const float*)d_in[14];
  const float* qW   = (const float*)d_in[15];
  const float* qb   = (const float*)d_in[16];
  float* out = (float*)d_out;

  // d_ws (fp8 fragments): kW1f 512KB | kW2f 1MB | kW3f 256KB | qWf 256KB = 2MB
  int* kW1f = (int*)d_ws;
  int* kW2f = kW1f + 131072;
  int* kW3f = kW2f + 262144;
  int* qWf  = kW3f + 65536;

  transform_all<<<512, 256, 0, stream>>>(kW1, kW2, kW3, qW, kW1f, kW2f, kW3f, qWf);

  policy_main<<<4096, 1024, 0, stream>>>(be, va, ph, tr, emb0, emb1, emb2, lng, lnb,
                                         kb1, kb2, kb3, qb, kW1f, kW2f, kW3f, qWf, out);
}

// Round 10
// 284.665 us; speedup vs baseline: 1.1075x; 1.1075x over previous
//
#include <hip/hip_runtime.h>
#include <hip/hip_bf16.h>
#include <cmath>

// Problem constants
constexpr int Bc = 128, Tc = 128, Ac = 16;
constexpr int Dc = 256, Hc = 512, Qc = 128, QIc = 512, Vc = 64, NTk = 13;
// Masked logits: ref emits -inf; harness needs finite there.
constexpr float NEG_BIG = -1e30f;
// fp8 scaling: weights x16, activations x16 (exact pow2).
// Descale folded into the MX scale operand (exact pow2 -> bitwise-equiv math):
//   L1/L2: scale 2^-4 -> acc = 16*W*X ; epilogue s = acc + 16*b
//   L3/Q : scale 2^-8 -> acc = W*X    ; epilogue s = acc + b
constexpr float ACT_SCALE = 16.f;

typedef unsigned int uint;
typedef uint uint2v __attribute__((ext_vector_type(2)));
typedef int i32x8 __attribute__((ext_vector_type(8)));
typedef float f32x4 __attribute__((ext_vector_type(4)));
typedef float f32x16 __attribute__((ext_vector_type(16)));

// MX-scaled fp8 MFMA. Uniform scale dword -> mapping-independent.
// 0x7F = 2^0, 0x7B = 2^-4, 0x77 = 2^-8 (E8M0). Verified r6-r8.
#define MFMA32S(a, b, c, SA) __builtin_amdgcn_mfma_scale_f32_32x32x64_f8f6f4( \
    (a), (b), (c), 0, 0, 0, (int)(SA), 0, 0x7F7F7F7F)
#define MFMA128Q(a, b, c) __builtin_amdgcn_mfma_scale_f32_16x16x128_f8f6f4( \
    (a), (b), (c), 0, 0, 0, 0x77777777, 0, 0x7F7F7F7F)

__device__ __forceinline__ unsigned short f2bfu(float f) {
  __hip_bfloat16 h = __float2bfloat16(f);
  return *(unsigned short*)&h;
}
__device__ __forceinline__ float bf2f(short s) {
  return __uint_as_float(((unsigned)(unsigned short)s) << 16);
}
__device__ __forceinline__ uint pack4_fp8(float a, float b, float c, float d) {
  uint v = 0;
  v = __builtin_amdgcn_cvt_pk_fp8_f32(a, b, v, 0);
  v = __builtin_amdgcn_cvt_pk_fp8_f32(c, d, v, 1);
  return v;
}

// ---------------------------------------------------------------------------
// Weight transform: fp32 [P][K][N] -> fp8 (x16) MFMA A-fragments.
// kW1/kW2/kW3: 32x32x64 frags: n = nt*32 + (lane&31), k = kc*64 + (lane>>5)*32 + byte.
// qW:          16x16x128 frags: n = nt*16 + (lane&15), k = kc*128 + (lane>>4)*32 + byte.
// Verified r1-r8 (A/B share one lane->k bijection; k-permutation-invariant).
// ---------------------------------------------------------------------------
__global__ void transform_all(const float* __restrict__ kW1, const float* __restrict__ kW2,
                              const float* __restrict__ kW3, const float* __restrict__ qW,
                              int* __restrict__ kW1f, int* __restrict__ kW2f,
                              int* __restrict__ kW3f, int* __restrict__ qWf) {
  int id = blockIdx.x * 256 + threadIdx.x;  // 131072 total
  int jh = id >> 16;                        // 0/1: 16B half of the 32B lane chunk
  int gid = id & 65535;
  const float* W;
  int* dst;
  int NT, KC, N, local;
  bool big;  // 32x32 layout?
  if (gid < 16384) {            // kW1: P4 x NT16 x KC4 (32x32)
    W = kW1; dst = kW1f; NT = 16; KC = 4; N = 512; local = gid; big = true;
  } else if (gid < 49152) {     // kW2: P4 x NT16 x KC8 (32x32)
    W = kW2; dst = kW2f; NT = 16; KC = 8; N = 512; local = gid - 16384; big = true;
  } else if (gid < 57344) {     // kW3: P4 x NT4 x KC8 (32x32)
    W = kW3; dst = kW3f; NT = 4; KC = 8; N = 128; local = gid - 49152; big = true;
  } else {                      // qW:  P4 x NT8 x KC4 (16x16)
    W = qW; dst = qWf; NT = 8; KC = 4; N = 128; local = gid - 57344; big = false;
  }
  int lane = local & 63;
  int frag = local >> 6;
  int kc = frag % KC;
  int rest = frag / KC;
  int nt = rest % NT;
  int pp = rest / NT;
  int K = KC * (big ? 64 : 128);
  int n, k0;
  if (big) { n = nt * 32 + (lane & 31); k0 = kc * 64 + (lane >> 5) * 32; }
  else     { n = nt * 16 + (lane & 15); k0 = kc * 128 + (lane >> 4) * 32; }
  k0 += jh * 16;
  const float* src = W + ((size_t)pp * K + k0) * N + n;
  int4 v;
  int vv[4];
#pragma unroll
  for (int jj = 0; jj < 4; ++jj) {
    float f0 = src[(size_t)(4 * jj + 0) * N] * ACT_SCALE;
    float f1 = src[(size_t)(4 * jj + 1) * N] * ACT_SCALE;
    float f2 = src[(size_t)(4 * jj + 2) * N] * ACT_SCALE;
    float f3 = src[(size_t)(4 * jj + 3) * N] * ACT_SCALE;
    vv[jj] = (int)pack4_fp8(f0, f1, f2, f3);
  }
  v.x = vv[0]; v.y = vv[1]; v.z = vv[2]; v.w = vv[3];
  *(int4*)(dst + (size_t)local * 8 + jh * 4) = v;
}

// ---------------------------------------------------------------------------
// 32x32x64 MX fp8 MFMA layer — occupancy build (32 waves/CU, r5 regime).
// kc=0 PEELED with a caller-prefetched weight fragment (wv0) issued just
// BEFORE the preceding __syncthreads (short live range — r7's early issue
// spilled 29MB) — the barrier's vmcnt drain absorbs the cold L2 latency.
// No LDS swizzle: BOTH XOR-swizzle attempts measured WORSE on hardware
// (r6 16B: conflicts 7.6M->18M; r9 32B: 7.6M->28.6M + 230MB spill) despite
// paper models predicting improvement — linear strides ==16 mod 128 B are
// the empirically best layout here. Bias loads in-loop (r6 hoist spilled).
// B-frag: lane (row=lane&31, q=lane>>5) reads 32B at row(+32*at), byte
// q*32 + kc*64. C/D: lane = action col; n = nt*32+(reg&3)+8*(reg>>2)+4q.
// OUTMODE: 0 = fp8 x16 hidden (s = acc + 16b, relu), 1 = bf16 KV (s = acc + b).
// ---------------------------------------------------------------------------
template <int KC, int AT, bool RELU, int OUTMODE, int SIN, int SOUT, unsigned SA>
__device__ __forceinline__ void layer32r(
    const char* __restrict__ aB, void* __restrict__ o0,
    const int* __restrict__ Wfi, const float* __restrict__ bias,
    int nt0, int at0, int lane, i32x8 wv0) {
  const int row = lane & 31, q = lane >> 5;
  const char* apA = aB + row * SIN + q * 32 + at0 * 32 * SIN;
  const int* wp = Wfi + (size_t)nt0 * KC * 512 + lane * 8;

  f32x16 acc[AT];
#pragma unroll
  for (int at = 0; at < AT; ++at)
#pragma unroll
    for (int r = 0; r < 16; ++r) acc[at][r] = 0.f;

  // ---- kc = 0 peeled: consumes the pre-barrier prefetched wv0 ----
#pragma unroll
  for (int at = 0; at < AT; ++at) {
    const char* pa = apA + at * 32 * SIN;
    uint4 u0 = *(const uint4*)(pa);
    uint4 u1 = *(const uint4*)(pa + 16);
    i32x8 bf;
    bf[0] = (int)u0.x; bf[1] = (int)u0.y; bf[2] = (int)u0.z; bf[3] = (int)u0.w;
    bf[4] = (int)u1.x; bf[5] = (int)u1.y; bf[6] = (int)u1.z; bf[7] = (int)u1.w;
    acc[at] = MFMA32S(wv0, bf, acc[at], SA);
  }

#pragma unroll 1
  for (int kc = 1; kc < KC; ++kc) {
    i32x8 wv = *(const i32x8*)(wp + kc * 512);
#pragma unroll
    for (int at = 0; at < AT; ++at) {
      const char* pa = apA + at * 32 * SIN + kc * 64;
      uint4 u0 = *(const uint4*)(pa);
      uint4 u1 = *(const uint4*)(pa + 16);
      i32x8 bf;
      bf[0] = (int)u0.x; bf[1] = (int)u0.y; bf[2] = (int)u0.z; bf[3] = (int)u0.w;
      bf[4] = (int)u1.x; bf[5] = (int)u1.y; bf[6] = (int)u1.z; bf[7] = (int)u1.w;
      acc[at] = MFMA32S(wv, bf, acc[at], SA);
    }
  }

#pragma unroll
  for (int at = 0; at < AT; ++at) {
    const int rowout = (at0 + at) * 32 + row;
    const int tb = nt0 * 32 + 4 * q;
#pragma unroll
    for (int j = 0; j < 4; ++j) {
      const int nb = tb + 8 * j;  // 4 consecutive outdims start here
      float4 bv = *(const float4*)(bias + nb);
      if (OUTMODE == 0) {
        float s0 = fmaf(bv.x, 16.f, acc[at][4 * j + 0]);
        float s1 = fmaf(bv.y, 16.f, acc[at][4 * j + 1]);
        float s2 = fmaf(bv.z, 16.f, acc[at][4 * j + 2]);
        float s3 = fmaf(bv.w, 16.f, acc[at][4 * j + 3]);
        if (RELU) {
          s0 = fmaxf(s0, 0.f); s1 = fmaxf(s1, 0.f);
          s2 = fmaxf(s2, 0.f); s3 = fmaxf(s3, 0.f);
        }
        *(uint*)((char*)o0 + rowout * SOUT + nb) = pack4_fp8(s0, s1, s2, s3);
      } else {
        float s0 = acc[at][4 * j + 0] + bv.x;
        float s1 = acc[at][4 * j + 1] + bv.y;
        float s2 = acc[at][4 * j + 2] + bv.z;
        float s3 = acc[at][4 * j + 3] + bv.w;
        uint2v u;
        u.x = ((uint)f2bfu(s1) << 16) | f2bfu(s0);
        u.y = ((uint)f2bfu(s3) << 16) | f2bfu(s2);
        *(uint2v*)((short*)o0 + rowout * SOUT + nb) = u;
      }
    }
  }
}

// ---------------------------------------------------------------------------
// 16x16x128 query head, rolled (waves 8-15, runs beside L3). Verified layout.
// Scale 2^-8 folded -> plain add epilogue. kc=0 peeled with prefetched wv0.
// ---------------------------------------------------------------------------
template <int KC, int SIN, int SOUT, int CMASK>
__device__ __forceinline__ void layer128r(
    const char* __restrict__ aB, float* __restrict__ o0,
    const int* __restrict__ Wfi, const float* __restrict__ bias,
    int nt0, int lane, i32x8 wv0) {
  const int c = lane & 15, q = lane >> 4;
  const int sw = (c & 1) << 4;
  const char* ap = aB + (c & CMASK) * SIN + q * 32;
  const int* wp = Wfi + (size_t)nt0 * KC * 512 + lane * 8;

  f32x4 acc;
#pragma unroll
  for (int r = 0; r < 4; ++r) acc[r] = 0.f;

  {
    uint4 u0 = *(const uint4*)(ap + sw);
    uint4 u1 = *(const uint4*)(ap + (16 ^ sw));
    i32x8 bf;
    bf[0] = (int)u0.x; bf[1] = (int)u0.y; bf[2] = (int)u0.z; bf[3] = (int)u0.w;
    bf[4] = (int)u1.x; bf[5] = (int)u1.y; bf[6] = (int)u1.z; bf[7] = (int)u1.w;
    acc = MFMA128Q(wv0, bf, acc);
  }

#pragma unroll 1
  for (int kc = 1; kc < KC; ++kc) {
    i32x8 wv = *(const i32x8*)(wp + kc * 512);
    const char* pa = ap + kc * 128;
    uint4 u0 = *(const uint4*)(pa + sw);
    uint4 u1 = *(const uint4*)(pa + (16 ^ sw));
    i32x8 bf;
    bf[0] = (int)u0.x; bf[1] = (int)u0.y; bf[2] = (int)u0.z; bf[3] = (int)u0.w;
    bf[4] = (int)u1.x; bf[5] = (int)u1.y; bf[6] = (int)u1.z; bf[7] = (int)u1.w;
    acc = MFMA128Q(wv, bf, acc);
  }

  const int nb = nt0 * 16 + 4 * q;
  float4 bv = *(const float4*)(bias + nb);
  if (c < 4) {  // only real token rows
    float4 st;
    st.x = acc[0] + bv.x;
    st.y = acc[1] + bv.y;
    st.z = acc[2] + bv.z;
    st.w = acc[3] + bv.w;
    *(float4*)(o0 + c * SOUT + nb) = st;
  }
}

// ---------------------------------------------------------------------------
// Main fused kernel: 1024 threads (16 waves), 64 rows (4 tokens x 16 actions).
// launch_bounds(1024,8): VGPR cap 64 -> 2 blocks/CU = 32 waves/CU (HW max).
// Each layer's kc=0 weight fragment is loaded just BEFORE the preceding
// barrier (short live range; r7's early issue cost 29MB of spill).
// phase = blockIdx&3: per-XCD one phase, 512KB fp8 weight set L2-resident.
// Session end-state (r10 = r8 restored): MFMA at MX floor (52us, 25%),
// occupancy at HW max, no pipe >35% — structural plateau for this design.
// ---------------------------------------------------------------------------
constexpr int SX = 272;   // Xs row stride bytes  (256 data + 16; ==16 mod 128)
constexpr int SH = 528;   // H1/H2 row stride     (512 data + 16; ==16 mod 128)
constexpr int SBE = 544;  // beAb row stride (16x16 path, (c&1) swizzled)
constexpr int SKV = 136;  // KV stride (bf16 elems, linear)
constexpr int SQY = 132;  // QY stride (fp32 elems, linear)

__global__ __launch_bounds__(1024, 8) void policy_main(
    const float* __restrict__ be, const int* __restrict__ va,
    const int* __restrict__ phase, const int* __restrict__ trick,
    const float* __restrict__ emb0, const float* __restrict__ emb1,
    const float* __restrict__ emb2, const float* __restrict__ ln_g,
    const float* __restrict__ ln_b,
    const float* __restrict__ kb1, const float* __restrict__ kb2,
    const float* __restrict__ kb3, const float* __restrict__ qb,
    const int* __restrict__ kW1f, const int* __restrict__ kW2f,
    const int* __restrict__ kW3f, const int* __restrict__ qWf,
    float* __restrict__ out) {
  __shared__ __align__(16) char bufA[64 * SH];   // Xs [64][SX] then H2 [64][SH]
  __shared__ __align__(16) char bufB[64 * SH];   // H1 [64][SH]; then KV [64][SKV] bf16
  __shared__ __align__(16) char beAb[4 * SBE];   // be tokens fp8 (4 rows, swizzled)
  __shared__ __align__(16) float QYs[4 * SQY];
  __shared__ float attn_s[64];
  __shared__ int inval_s[64];
  __shared__ int ph_s[4], tr_s[4];

  char* Xs = bufA;
  char* H2 = bufA;
  char* H1 = bufB;
  short* KV = (short*)bufB;  // H1 dead after layer2

  const int tid = threadIdx.x;
  const int lane = tid & 63;
  const int wu = __builtin_amdgcn_readfirstlane(tid >> 6);  // wave id -> SGPR
  const int p = blockIdx.x & 3;
  const int g = blockIdx.x >> 2;
  const int b = g >> 3;
  const int t0 = p * 32 + (g & 7) * 4;
  const int bt0 = b * Tc + t0;

  // ---- stage 0 (no internal barrier): masks, phase/trick, beA, LN->Xs ----
  if (tid < 64) {
    inval_s[tid] = (va[((size_t)bt0 * Ac + tid) * 3] == -1);
  } else if (tid < 68) {
    ph_s[tid - 64] = phase[bt0 + tid - 64];
  } else if (tid < 72) {
    tr_s[tid - 68] = trick[bt0 + tid - 68];
  }
  if (tid < 128) {  // beA: 4 token rows x 512 dims fp8 (x16), swizzled 16B units
    const int tok = tid >> 5, li = tid & 31;
    const float4* bp4 = (const float4*)(be + ((size_t)(bt0 + tok)) * QIc + li * 16);
    float4 a0 = bp4[0], a1 = bp4[1], a2 = bp4[2], a3 = bp4[3];
    uint4 v;
    v.x = pack4_fp8(a0.x * ACT_SCALE, a0.y * ACT_SCALE, a0.z * ACT_SCALE, a0.w * ACT_SCALE);
    v.y = pack4_fp8(a1.x * ACT_SCALE, a1.y * ACT_SCALE, a1.z * ACT_SCALE, a1.w * ACT_SCALE);
    v.z = pack4_fp8(a2.x * ACT_SCALE, a2.y * ACT_SCALE, a2.z * ACT_SCALE, a2.w * ACT_SCALE);
    v.w = pack4_fp8(a3.x * ACT_SCALE, a3.y * ACT_SCALE, a3.z * ACT_SCALE, a3.w * ACT_SCALE);
    *(uint4*)(beAb + tok * SBE + ((li * 16) ^ ((tok & 1) << 4))) = v;
  }
  {
    // embed-sum + LayerNorm -> Xs fp8 x16 (16 thr/row x 16 dims), linear layout
    const int r = tid >> 4, part = tid & 15, d0 = part * 16;
    const int* vp = va + ((size_t)bt0 * Ac + r) * 3;
    int i0 = min(max(vp[0], 0), Vc - 1);
    int i1 = min(max(vp[1], 0), Vc - 1);
    int i2 = min(max(vp[2], 0), Vc - 1);
    const float4* e0 = (const float4*)(emb0 + i0 * Dc + d0);
    const float4* e1 = (const float4*)(emb1 + i1 * Dc + d0);
    const float4* e2 = (const float4*)(emb2 + i2 * Dc + d0);
    float xv[16];
    float sum = 0.f, ss = 0.f;
#pragma unroll
    for (int j = 0; j < 4; ++j) {
      float4 v0 = e0[j], v1 = e1[j], v2 = e2[j];
      float4 v;
      v.x = v0.x + v1.x + v2.x; v.y = v0.y + v1.y + v2.y;
      v.z = v0.z + v1.z + v2.z; v.w = v0.w + v1.w + v2.w;
      xv[j * 4 + 0] = v.x; xv[j * 4 + 1] = v.y; xv[j * 4 + 2] = v.z; xv[j * 4 + 3] = v.w;
      sum += v.x + v.y + v.z + v.w;
      ss += v.x * v.x + v.y * v.y + v.z * v.z + v.w * v.w;
    }
    sum += __shfl_xor(sum, 1); sum += __shfl_xor(sum, 2);
    sum += __shfl_xor(sum, 4); sum += __shfl_xor(sum, 8);
    ss += __shfl_xor(ss, 1);   ss += __shfl_xor(ss, 2);
    ss += __shfl_xor(ss, 4);   ss += __shfl_xor(ss, 8);
    const float mu = sum / (float)Dc;
    const float rstd = rsqrtf(ss / (float)Dc - mu * mu + 1e-5f);
    uint dw[4];
#pragma unroll
    for (int j = 0; j < 4; ++j) {
      float4 gg = *(const float4*)(ln_g + d0 + 4 * j);
      float4 bb = *(const float4*)(ln_b + d0 + 4 * j);
      float y0 = ((xv[4 * j + 0] - mu) * rstd * gg.x + bb.x) * ACT_SCALE;
      float y1 = ((xv[4 * j + 1] - mu) * rstd * gg.y + bb.y) * ACT_SCALE;
      float y2 = ((xv[4 * j + 2] - mu) * rstd * gg.z + bb.z) * ACT_SCALE;
      float y3 = ((xv[4 * j + 3] - mu) * rstd * gg.w + bb.w) * ACT_SCALE;
      dw[j] = pack4_fp8(y0, y1, y2, y3);
    }
    uint4 v;
    v.x = dw[0]; v.y = dw[1]; v.z = dw[2]; v.w = dw[3];
    *(uint4*)(Xs + r * SX + d0) = v;
  }

  // ---- L1 kc=0 prefetch: issued just before the barrier (short live range;
  //      latency folds into the barrier's vmcnt drain) ----
  const int* w1base = kW1f + (size_t)p * 32768;
  i32x8 w1 = *(const i32x8*)(w1base + (size_t)wu * 4 * 512 + lane * 8);
  __syncthreads();

  // ---- layer1: X(64x256) @ kW1 -> H1(64x512) relu. 16 waves x 1nt x 2at ----
  layer32r<4, 2, true, 0, SX, SH, 0x7B7B7B7Bu>(
      Xs, H1, w1base, kb1 + p * Hc, wu, 0, lane, w1);

  // ---- L2 kc=0 prefetch (pre-barrier; acc regs are dead here) ----
  const int* w2base = kW2f + (size_t)p * 65536;
  i32x8 w2 = *(const i32x8*)(w2base + (size_t)wu * 8 * 512 + lane * 8);
  __syncthreads();

  // ---- layer2: H1(64x512) @ kW2 -> H2(64x512) relu ----
  layer32r<8, 2, true, 0, SH, SH, 0x7B7B7B7Bu>(
      H1, H2, w2base, kb2 + p * Hc, wu, 0, lane, w2);

  // ---- L3/q kc=0 prefetch (wave-uniform select, pre-barrier) ----
  const int* w3base = (wu < 8) ? (kW3f + (size_t)p * 16384) : (qWf + (size_t)p * 16384);
  const int w3off = (wu < 8) ? ((wu >> 1) * 8 * 512) : ((wu - 8) * 4 * 512);
  i32x8 w3 = *(const i32x8*)(w3base + (size_t)w3off + lane * 8);
  __syncthreads();

  // ---- layer3 (waves 0-7) -> KV bf16 ; query (waves 8-15) -> QY fp32 ----
  if (wu < 8) {
    layer32r<8, 1, false, 1, SH, SKV, 0x77777777u>(
        H2, (void*)KV, w3base, kb3 + p * Qc, wu >> 1, wu & 1, lane, w3);
  } else {
    layer128r<4, SBE, SQY, 3>(beAb, QYs, w3base, qb + p * Qc, wu - 8, lane, w3);
  }
  __syncthreads();

  // ---- attn[r] = <QY[tok], KV[r]> / sqrt(Q) (16 thr/row x 8 dims) ----
  {
    const int r = tid >> 4, part = tid & 15, tok = r >> 4;
    uint4 kk = *(const uint4*)(KV + r * SKV + part * 8);
    const float4* qp4 = (const float4*)(QYs + tok * SQY + part * 8);
    float4 q0 = qp4[0], q1 = qp4[1];
    float s = 0.f;
    s += bf2f((short)(kk.x & 0xffff)) * q0.x;
    s += bf2f((short)(kk.x >> 16)) * q0.y;
    s += bf2f((short)(kk.y & 0xffff)) * q0.z;
    s += bf2f((short)(kk.y >> 16)) * q0.w;
    s += bf2f((short)(kk.z & 0xffff)) * q1.x;
    s += bf2f((short)(kk.z >> 16)) * q1.y;
    s += bf2f((short)(kk.w & 0xffff)) * q1.z;
    s += bf2f((short)(kk.w >> 16)) * q1.w;
    s += __shfl_xor(s, 1); s += __shfl_xor(s, 2);
    s += __shfl_xor(s, 4); s += __shfl_xor(s, 8);
    if (part == 0) attn_s[r] = s * 0.08838834764831845f;  // 1/sqrt(128)
  }
  __syncthreads();

  // ---- mask, signal weight, log_softmax, store (wave-parallel: 16 thr/token) ----
  if (tid < 64) {
    const int tok = tid >> 4, a = tid & 15;
    const int bt = bt0 + tok;
    const int iv = inval_s[tid];
    float av = iv ? NEG_BIG : attn_s[tid];
    int inv = iv;
    inv += __shfl_xor(inv, 1); inv += __shfl_xor(inv, 2);
    inv += __shfl_xor(inv, 4); inv += __shfl_xor(inv, 8);
    const int nv = 16 - inv;
    if (a == 0 && ph_s[tok] == 1) {
      const int nt = NTk - tr_s[tok];
      float dp = 1.f;
      for (int i = 0; i < nt; ++i) dp *= 0.6f;
      const float ps = 0.4f / (1.f - dp);
      float wgt = (nv == 1) ? 0.f : logf(fmaxf((1.f - ps) / ps * ((float)nv - 1.f), 1e-5f));
      av += wgt;
    }
    float m = av;
    m = fmaxf(m, __shfl_xor(m, 1)); m = fmaxf(m, __shfl_xor(m, 2));
    m = fmaxf(m, __shfl_xor(m, 4)); m = fmaxf(m, __shfl_xor(m, 8));
    float e = expf(av - m);
    float se = e;
    se += __shfl_xor(se, 1); se += __shfl_xor(se, 2);
    se += __shfl_xor(se, 4); se += __shfl_xor(se, 8);
    const float lse = logf(se) + m;
    out[bt * Ac + a] = iv ? NEG_BIG : (av - lse);
  }
}

extern "C" void kernel_launch(void* const* d_in, const int* in_sizes, int n_in,
                              void* d_out, int out_size, void* d_ws, size_t ws_size,
                              hipStream_t stream) {
  const float* be   = (const float*)d_in[0];
  const int*   va   = (const int*)d_in[1];
  const int*   ph   = (const int*)d_in[2];
  const int*   tr   = (const int*)d_in[3];
  const float* emb0 = (const float*)d_in[4];
  const float* emb1 = (const float*)d_in[5];
  const float* emb2 = (const float*)d_in[6];
  const float* lng  = (const float*)d_in[7];
  const float* lnb  = (const float*)d_in[8];
  const float* kW1  = (const float*)d_in[9];
  const float* kb1  = (const float*)d_in[10];
  const float* kW2  = (const float*)d_in[11];
  const float* kb2  = (const float*)d_in[12];
  const float* kW3  = (const float*)d_in[13];
  const float* kb3  = (const float*)d_in[14];
  const float* qW   = (const float*)d_in[15];
  const float* qb   = (const float*)d_in[16];
  float* out = (float*)d_out;

  // d_ws (fp8 fragments): kW1f 512KB | kW2f 1MB | kW3f 256KB | qWf 256KB = 2MB
  int* kW1f = (int*)d_ws;
  int* kW2f = kW1f + 131072;
  int* kW3f = kW2f + 262144;
  int* qWf  = kW3f + 65536;

  transform_all<<<512, 256, 0, stream>>>(kW1, kW2, kW3, qW, kW1f, kW2f, kW3f, qWf);

  policy_main<<<4096, 1024, 0, stream>>>(be, va, ph, tr, emb0, emb1, emb2, lng, lnb,
                                         kb1, kb2, kb3, qb, kW1f, kW2f, kW3f, qWf, out);
}